// Round 5
// baseline (145.952 us; speedup 1.0000x reference)
//
#include <hip/hip_runtime.h>
#include <stdint.h>

// PersonalMed on MI355X. B=48,V=16,M=32,C=48,CM=8,D=128,OUT=256. f32 in/out.
// Round-5: fused GRU with a real software pipeline.
//  - RAW barrier (lgkmcnt-only drain) so prefetched global loads stay in
//    flight across steps (the __syncthreads vmcnt(0) drain was the round-4
//    bottleneck: 4400 cyc/step vs 930 cyc MFMA floor).
//  - gi double-buffered one step ahead: gates at t consume gi(t) built at
//    end of iter t-1; the 12 independent gi MFMAs hide ds_read latency.
//  - broadcast streams (vis_org, 3 of 5 mode-0 streams): constant gi hoisted
//    out of the loop (computed once).
//  - per wave: 48 output cols of r,z,n in VGPR-resident Wih/Whh frags.

typedef unsigned short u16;
typedef uint32_t u32;
typedef short bf8 __attribute__((ext_vector_type(8)));   // 8 bf16 = 4 VGPRs
typedef float f4 __attribute__((ext_vector_type(4)));

static __device__ __forceinline__ float bf2f(u16 b){ u32 u=((u32)b)<<16; float f; __builtin_memcpy(&f,&u,4); return f; }
static __device__ __forceinline__ u16 f2bf(float f){ u32 u; __builtin_memcpy(&u,&f,4); u32 r=(u+0x7fffu+((u>>16)&1u))>>16; return (u16)r; }
static __device__ __forceinline__ float bflo(u32 u){ u32 x=u<<16; float f; __builtin_memcpy(&f,&x,4); return f; }
static __device__ __forceinline__ float bfhi(u32 u){ u32 x=u&0xffff0000u; float f; __builtin_memcpy(&f,&x,4); return f; }
static __device__ __forceinline__ f4 mfma16(bf8 a, bf8 b, f4 c){ return __builtin_amdgcn_mfma_f32_16x16x32_bf16(a,b,c,0,0,0); }
static __device__ __forceinline__ float sigm(float x){ return 1.0f/(1.0f+__expf(-x)); }
static __device__ __forceinline__ float tanh_f(float x){ return 1.0f-2.0f/(__expf(2.0f*x)+1.0f); }

// ---------------- f32->bf16 prep (GRU weights + emb_mon tables) ----------------
__global__ __launch_bounds__(256) void k_prep(const float* __restrict__ s0, const float* __restrict__ s1,
                                              const float* __restrict__ s2, const float* __restrict__ s3,
                                              const float* __restrict__ s4,
                                              u16* __restrict__ d0, u16* __restrict__ d1,
                                              u16* __restrict__ d2, u16* __restrict__ d3,
                                              u16* __restrict__ d4){
  int y = blockIdx.y;
  const float* src = y==0?s0 : y==1?s1 : y==2?s2 : y==3?s3 : s4;
  u16* dst         = y==0?d0 : y==1?d1 : y==2?d2 : y==3?d3 : d4;
  int n4 = (y<2 ? 245760 : y<4 ? 344064 : 512000) >> 2;
  int i = blockIdx.x*256 + threadIdx.x;
  if (i < n4){
    float4 v = *(const float4*)(src + (size_t)i*4);
    ushort4 o = { f2bf(v.x), f2bf(v.y), f2bf(v.z), f2bf(v.w) };
    *(ushort4*)(dst + (size_t)i*4) = o;
  }
}

// ---------------- front: visit embedding bags + weight/age linears ----------------
// grid (768,5) block 128. y<3: vis_org[y][row][d]; y>=3: hin2T slots 5,6.
__global__ __launch_bounds__(128) void k_front(const int* __restrict__ vids,
                                               const float* __restrict__ embv,
                                               const float* __restrict__ wv, const float* __restrict__ av,
                                               const float* __restrict__ ww, const float* __restrict__ wb,
                                               const float* __restrict__ aw, const float* __restrict__ ab,
                                               u16* __restrict__ vis_org, u16* __restrict__ hin2T){
  __shared__ int ids[48];
  int y = blockIdx.y, row = blockIdx.x, d = threadIdx.x;
  if (y < 3){
    if (d < 48) ids[d] = vids[((size_t)y*768 + row)*48 + d];
    __syncthreads();
    const float* eb = embv + (size_t)y*2000*128;
    float acc = 0.f;
    #pragma unroll 4
    for (int c = 0; c < 48; ++c){ int id = ids[c]; if (id) acc += eb[(size_t)id*128 + d]; }
    vis_org[((size_t)y*768 + row)*128 + d] = f2bf(acc);
  } else {
    int sidx = y - 3;
    const float* vals = sidx ? av : wv;
    const float* wgt  = sidx ? aw : ww;
    const float* bias = sidx ? ab : wb;
    float v = vals[row];
    float h = (v != 0.f) ? (v * wgt[d] + bias[d]) : 0.f;
    int b = row >> 4, vv = row & 15;
    hin2T[((size_t)(5+sidx)*768 + (size_t)vv*48 + b)*128 + d] = f2bf(h);
  }
}

// ---------------- monitor embedding bag ----------------
// grid (3072,2), block 256: 8 rows/block, 32 lanes/row, 4 d/lane.
__global__ __launch_bounds__(256) void k_embed_mon(const int* __restrict__ mids,
                                                   const u16* __restrict__ embm_b,
                                                   u16* __restrict__ mon_xT){
  int p = blockIdx.y;
  int rid = threadIdx.x >> 5, lane32 = threadIdx.x & 31, d0 = lane32*4;
  __shared__ int ids[8][16];
  if (threadIdx.x < 128){
    int rr = threadIdx.x >> 4, c = threadIdx.x & 15;
    int f = 2*p + (c>>3), cm = c & 7;
    ids[rr][c] = mids[((size_t)f*24576 + (size_t)blockIdx.x*8 + rr)*8 + cm];
  }
  __syncthreads();
  const u16* e1 = embm_b + (size_t)(2*p)*1000*128;
  const u16* e2 = embm_b + (size_t)(2*p+1)*1000*128;
  float a0=0.f,a1=0.f,a2=0.f,a3=0.f;
  #pragma unroll
  for (int c = 0; c < 8; ++c){
    int i1 = ids[rid][c], i2 = ids[rid][8+c];
    if (i1 && i2){
      uint2 a = *(const uint2*)(e1 + (size_t)i1*128 + d0);
      uint2 b = *(const uint2*)(e2 + (size_t)i2*128 + d0);
      a0 += bflo(a.x)*bflo(b.x); a1 += bfhi(a.x)*bfhi(b.x);
      a2 += bflo(a.y)*bflo(b.y); a3 += bfhi(a.y)*bfhi(b.y);
    }
  }
  size_t nm = (size_t)blockIdx.x*8 + rid;
  int bv = (int)(nm >> 5), m = (int)(nm & 31);
  ushort4 o = { f2bf(a0), f2bf(a1), f2bf(a2), f2bf(a3) };
  *(ushort4*)(mon_xT + (size_t)p*24576*128 + ((size_t)m*768 + bv)*128 + d0) = o;
}

// ---------------- fused GRU (pipelined) ----------------
// mode 0: grid (48,5) T=32. s<2: A=mon_xT[s], rstride=768*128. s>=2:
//         A=vis_org[s-2], rstride=0 (gi constant). weights mgru[s];
//         out hin2T[slot], slot=0x32140 nibble, [v=(lq*4+r)*48 + b=g].
// mode 1: grid (3,7) T=16. A=hin2T[s], rstride=48*128; weights vgru[vi],
//         vi=0x6514320 nibble; out h2[s][b=g*16+lq*4+r][128].

// raw barrier: drain LDS only; global prefetch stays in flight (T4 idiom).
#define BARRIER() asm volatile("s_waitcnt lgkmcnt(0)\n\ts_barrier" ::: "memory")

#define ALOAD(D, tt) { int t_=(tt); if (t_>=T) t_=0; \
  const u16* p_ = ap + (size_t)t_*rstride; \
  D[0]=*(const bf8*)(p_); D[1]=*(const bf8*)(p_+32); \
  D[2]=*(const bf8*)(p_+64); D[3]=*(const bf8*)(p_+96); }

#define GIMM(G0,G1,G2,D) { \
  f4 t0_={biv[0],biv[0],biv[0],biv[0]}; G0=t0_; \
  f4 t1_={biv[1],biv[1],biv[1],biv[1]}; G1=t1_; \
  f4 t2_={biv[2],biv[2],biv[2],biv[2]}; G2=t2_; \
  G0=mfma16(D[0],wfi[0][0],G0); G0=mfma16(D[1],wfi[0][1],G0); \
  G0=mfma16(D[2],wfi[0][2],G0); G0=mfma16(D[3],wfi[0][3],G0); \
  G1=mfma16(D[0],wfi[1][0],G1); G1=mfma16(D[1],wfi[1][1],G1); \
  G1=mfma16(D[2],wfi[1][2],G1); G1=mfma16(D[3],wfi[1][3],G1); \
  G2=mfma16(D[0],wfi[2][0],G2); G2=mfma16(D[1],wfi[2][1],G2); \
  G2=mfma16(D[2],wfi[2][2],G2); G2=mfma16(D[3],wfi[2][3],G2); }

// declares a0_,a1_,a2_ (gh accumulators) + reads hf from hlds[cur]
#define GHRD() \
  bf8 hf0_=*(const bf8*)&hlds[cur][lr][lq*8]; \
  bf8 hf1_=*(const bf8*)&hlds[cur][lr][32+lq*8]; \
  bf8 hf2_=*(const bf8*)&hlds[cur][lr][64+lq*8]; \
  bf8 hf3_=*(const bf8*)&hlds[cur][lr][96+lq*8]; \
  f4 a0_={bhv[0],bhv[0],bhv[0],bhv[0]}; \
  f4 a1_={bhv[1],bhv[1],bhv[1],bhv[1]}; \
  f4 a2_={bhv[2],bhv[2],bhv[2],bhv[2]}; \
  a0_=mfma16(hf0_,wfh[0][0],a0_); a0_=mfma16(hf1_,wfh[0][1],a0_); \
  a0_=mfma16(hf2_,wfh[0][2],a0_); a0_=mfma16(hf3_,wfh[0][3],a0_); \
  a1_=mfma16(hf0_,wfh[1][0],a1_); a1_=mfma16(hf1_,wfh[1][1],a1_); \
  a1_=mfma16(hf2_,wfh[1][2],a1_); a1_=mfma16(hf3_,wfh[1][3],a1_); \
  a2_=mfma16(hf0_,wfh[2][0],a2_); a2_=mfma16(hf1_,wfh[2][1],a2_); \
  a2_=mfma16(hf2_,wfh[2][2],a2_); a2_=mfma16(hf3_,wfh[2][3],a2_);

// consumes G*, a*_ -> h_{t+1}; write LDS; raw barrier; flip cur
#define GATES(G0,G1,G2) { int nxt_=cur^1; \
  _Pragma("unroll") \
  for (int r=0;r<4;++r){ \
    float rr_=sigm(G0[r]+a0_[r]); \
    float zz_=sigm(G1[r]+a1_[r]); \
    float nn_=tanh_f(G2[r]+rr_*a2_[r]); \
    float hv_=(1.0f-zz_)*nn_+zz_*hp[r]; hp[r]=hv_; \
    hlds[nxt_][lq*4+r][w*16+lr]=f2bf(hv_); } \
  BARRIER(); cur=nxt_; }

#define STEP0(G0,G1,G2) { \
  f4 a0_={bhv[0],bhv[0],bhv[0],bhv[0]}; \
  f4 a1_={bhv[1],bhv[1],bhv[1],bhv[1]}; \
  f4 a2_={bhv[2],bhv[2],bhv[2],bhv[2]}; \
  GATES(G0,G1,G2); }

// full pipelined step: consume gi(t) from G*, rebuild G* = gi(t+2) from SN,
// then refill SN with A(t+4) (stays in flight 2 iterations).
#define STEPB(G0,G1,G2,SN,tt) { \
  GHRD(); \
  GATES(G0,G1,G2); \
  if ((tt)+2 < T){ GIMM(G0,G1,G2,SN); } \
  ALOAD(SN,(tt)+4); }

__global__ __launch_bounds__(512, 2) void k_gru(int mode,
    const u16* __restrict__ Asrc, const u16* __restrict__ Asrc2,
    const u16* __restrict__ Wih, const float* __restrict__ bih,
    const u16* __restrict__ Whh, const float* __restrict__ bhh,
    u16* __restrict__ hout, int T){
  int s = blockIdx.y, g = blockIdx.x;
  const u16* A; size_t rstride; u16* ho; int widx;
  if (mode == 0){
    if (s < 2){ A = Asrc + (size_t)s*24576*128; rstride = 768*128; }
    else      { A = Asrc2 + (size_t)(s-2)*768*128; rstride = 0; }
    widx = s;
    int slot = (0x32140u >> (4*s)) & 15;
    ho = hout + (size_t)slot*768*128;
  } else {
    A = Asrc + (size_t)s*768*128; rstride = 48*128;
    widx = (0x6514320u >> (4*s)) & 15;
    ho = hout + (size_t)s*48*128;
  }
  const u16* Wi = Wih + (size_t)widx*384*128;
  const u16* Wh = Whh + (size_t)widx*384*128;
  const float* bi = bih + (size_t)widx*384;
  const float* bh = bhh + (size_t)widx*384;

  int w = threadIdx.x >> 6, l = threadIdx.x & 63;
  int lr = l & 15, lq = l >> 4;

  // wave w owns gate-col-chunk w*16..+16 of r,z,n (tiles w, 8+w, 16+w)
  bf8 wfi[3][4], wfh[3][4]; float biv[3], bhv[3];
  #pragma unroll
  for (int j = 0; j < 3; ++j){
    int colb = (w + 8*j)*16;
    const u16* wpi = Wi + (size_t)(colb + lr)*128 + lq*8;
    const u16* wph = Wh + (size_t)(colb + lr)*128 + lq*8;
    #pragma unroll
    for (int kt = 0; kt < 4; ++kt){
      wfi[j][kt] = *(const bf8*)(wpi + kt*32);
      wfh[j][kt] = *(const bf8*)(wph + kt*32);
    }
    biv[j] = bi[colb + lr];
    bhv[j] = bh[colb + lr];
  }

  const u16* ap = A + (size_t)(g*16 + lr)*128 + lq*8;
  __shared__ u16 hlds[2][16][132];   // 66-dword row stride: conflict-free b128
  float hp[4] = {0.f,0.f,0.f,0.f};
  int cur = 0;

  if (rstride){
    bf8 S0[4], S1[4];
    f4 gE0,gE1,gE2, gO0,gO1,gO2;
    ALOAD(S0,0); ALOAD(S1,1);
    GIMM(gE0,gE1,gE2,S0); ALOAD(S0,2);      // gi(0); A(2) in flight
    GIMM(gO0,gO1,gO2,S1); ALOAD(S1,3);      // gi(1); A(3) in flight
    STEP0(gE0,gE1,gE2);                     // step 0 (gh = bhh)
    GIMM(gE0,gE1,gE2,S0); ALOAD(S0,4);      // gi(2); A(4) in flight
    STEPB(gO0,gO1,gO2,S1,1);                // consume gi(1), build gi(3)
    for (int t = 2; t < T; t += 2){
      STEPB(gE0,gE1,gE2,S0,t);
      STEPB(gO0,gO1,gO2,S1,t+1);
    }
  } else {
    bf8 S0[4];
    f4 gE0,gE1,gE2;
    ALOAD(S0,0);
    GIMM(gE0,gE1,gE2,S0);                   // constant gi, computed once
    STEP0(gE0,gE1,gE2);
    for (int t = 1; t < T; ++t){
      GHRD();
      GATES(gE0,gE1,gE2);
    }
  }

  if (mode == 0){
    #pragma unroll
    for (int r = 0; r < 4; ++r)
      ho[((size_t)(lq*4+r)*48 + g)*128 + w*16 + lr] = f2bf(hp[r]);
  } else {
    #pragma unroll
    for (int r = 0; r < 4; ++r)
      ho[((size_t)(g*16 + lq*4 + r))*128 + w*16 + lr] = f2bf(hp[r]);
  }
}

// ---------------- final projection ----------------
__global__ __launch_bounds__(256) void k_final(const u16* __restrict__ h2,
                                               const float* __restrict__ W,
                                               const float* __restrict__ Bias,
                                               float* __restrict__ out){
  int b = blockIdx.x, t = threadIdx.x;
  __shared__ float emb[896];
  for (int i = t; i < 896; i += 256){
    int j = i >> 7, d = i & 127;
    float v = bf2f(h2[((size_t)j*48 + b)*128 + d]);
    if (j >= 1 && j <= 3) v *= 2.0f;   // slots 1..3 appear twice in reference sum
    emb[i] = fmaxf(v, 0.f);
  }
  __syncthreads();
  float acc = Bias[t];
  const float* wp = W + (size_t)t*896;
  for (int i = 0; i < 896; i += 8){
    float4 w0 = *(const float4*)(wp + i);
    float4 w1 = *(const float4*)(wp + i + 4);
    acc += w0.x*emb[i]   + w0.y*emb[i+1] + w0.z*emb[i+2] + w0.w*emb[i+3];
    acc += w1.x*emb[i+4] + w1.y*emb[i+5] + w1.z*emb[i+6] + w1.w*emb[i+7];
  }
  out[(size_t)b*256 + t] = acc;
}

extern "C" void kernel_launch(void* const* d_in, const int* in_sizes, int n_in,
                              void* d_out, int out_size, void* d_ws, size_t ws_size,
                              hipStream_t stream){
  const int*   visit_ids   = (const int*)d_in[0];
  const int*   mon_ids     = (const int*)d_in[1];
  const float* weight_vals = (const float*)d_in[2];
  const float* age_vals    = (const float*)d_in[3];
  const float* emb_visit   = (const float*)d_in[4];
  const float* emb_mon     = (const float*)d_in[5];
  const float* mgru_Wih    = (const float*)d_in[6];
  const float* mgru_Whh    = (const float*)d_in[7];
  const float* mgru_bih    = (const float*)d_in[8];
  const float* mgru_bhh    = (const float*)d_in[9];
  const float* vgru_Wih    = (const float*)d_in[10];
  const float* vgru_Whh    = (const float*)d_in[11];
  const float* vgru_bih    = (const float*)d_in[12];
  const float* vgru_bhh    = (const float*)d_in[13];
  const float* fc_w_w      = (const float*)d_in[14];
  const float* fc_w_b      = (const float*)d_in[15];
  const float* fc_a_w      = (const float*)d_in[16];
  const float* fc_a_b      = (const float*)d_in[17];
  const float* fc_out_w    = (const float*)d_in[18];
  const float* fc_out_b    = (const float*)d_in[19];

  char* ws = (char*)d_ws;
  size_t o = 0;
  u16* mWih_b  = (u16*)(ws+o); o += 5ull*384*128*2;
  u16* mWhh_b  = (u16*)(ws+o); o += 5ull*384*128*2;
  u16* vWih_b  = (u16*)(ws+o); o += 7ull*384*128*2;
  u16* vWhh_b  = (u16*)(ws+o); o += 7ull*384*128*2;
  u16* embm_b  = (u16*)(ws+o); o += 4ull*1000*128*2;
  u16* mon_xT  = (u16*)(ws+o); o += 2ull*24576*128*2;    // [p][m*768+bv][128]
  u16* vis_org = (u16*)(ws+o); o += 3ull*768*128*2;
  u16* hin2T   = (u16*)(ws+o); o += 7ull*768*128*2;      // [slot][v*48+b][128]
  u16* h2      = (u16*)(ws+o); o += 7ull*48*128*2;       // ~17.6 MB total

  k_prep<<<dim3(500,5), 256, 0, stream>>>(mgru_Wih, mgru_Whh, vgru_Wih, vgru_Whh, emb_mon,
                                          mWih_b, mWhh_b, vWih_b, vWhh_b, embm_b);
  k_front<<<dim3(768,5), 128, 0, stream>>>(visit_ids, emb_visit,
                                           weight_vals, age_vals, fc_w_w, fc_w_b, fc_a_w, fc_a_b,
                                           vis_org, hin2T);
  k_embed_mon<<<dim3(3072,2), 256, 0, stream>>>(mon_ids, embm_b, mon_xT);
  // monitor-level fused GRU: 5 streams -> hin2T slots {0,4,1,2,3}
  k_gru<<<dim3(48,5), 512, 0, stream>>>(0, mon_xT, vis_org,
                                        mWih_b, mgru_bih, mWhh_b, mgru_bhh, hin2T, 32);
  // visit-level fused GRU: 7 streams -> h2
  k_gru<<<dim3(3,7), 512, 0, stream>>>(1, hin2T, (const u16*)0,
                                       vWih_b, vgru_bih, vWhh_b, vgru_bhh, h2, 16);
  k_final<<<48, 256, 0, stream>>>(h2, fc_out_w, fc_out_b, (float*)d_out);
}

// Round 6
// 132.909 us; speedup vs baseline: 1.0981x; 1.0981x over previous
//
#include <hip/hip_runtime.h>
#include <stdint.h>

// PersonalMed on MI355X. B=48,V=16,M=32,C=48,CM=8,D=128,OUT=256. f32 in/out.
// Round-6: round-5 pipeline + FAST GATE ACTIVATIONS.
// Root cause of the 60us k_gru plateau (r2-r5): no -ffast-math, so every
// sigmoid/tanh division compiled to the IEEE div sequence (~12 ops, ~60cyc
// latency) x 12 gate values/thread/step -> ~1700 VALU cyc/step/SIMD.
// Fix: v_rcp_f32 + v_exp_f32 (2^x) single-instruction approximations.

typedef unsigned short u16;
typedef uint32_t u32;
typedef short bf8 __attribute__((ext_vector_type(8)));   // 8 bf16 = 4 VGPRs
typedef float f4 __attribute__((ext_vector_type(4)));

static __device__ __forceinline__ float bf2f(u16 b){ u32 u=((u32)b)<<16; float f; __builtin_memcpy(&f,&u,4); return f; }
static __device__ __forceinline__ u16 f2bf(float f){ u32 u; __builtin_memcpy(&u,&f,4); u32 r=(u+0x7fffu+((u>>16)&1u))>>16; return (u16)r; }
static __device__ __forceinline__ float bflo(u32 u){ u32 x=u<<16; float f; __builtin_memcpy(&f,&x,4); return f; }
static __device__ __forceinline__ float bfhi(u32 u){ u32 x=u&0xffff0000u; float f; __builtin_memcpy(&f,&x,4); return f; }
static __device__ __forceinline__ f4 mfma16(bf8 a, bf8 b, f4 c){ return __builtin_amdgcn_mfma_f32_16x16x32_bf16(a,b,c,0,0,0); }

#if __has_builtin(__builtin_amdgcn_exp2f)
static __device__ __forceinline__ float fexp2(float x){ return __builtin_amdgcn_exp2f(x); }
#else
static __device__ __forceinline__ float fexp2(float x){ float r; asm volatile("v_exp_f32 %0, %1" : "=v"(r) : "v"(x)); return r; }
#endif
#if __has_builtin(__builtin_amdgcn_rcpf)
static __device__ __forceinline__ float frcp(float x){ return __builtin_amdgcn_rcpf(x); }
#else
static __device__ __forceinline__ float frcp(float x){ float r; asm volatile("v_rcp_f32 %0, %1" : "=v"(r) : "v"(x)); return r; }
#endif

#define LOG2E 1.44269504089f
// sigmoid(x) = 1/(1+2^(-x*log2e));  tanh(x) = 1 - 2/(1+2^(2x*log2e))
static __device__ __forceinline__ float sigm(float x){ return frcp(1.0f + fexp2(-LOG2E*x)); }
static __device__ __forceinline__ float tanh_f(float x){ return 1.0f - 2.0f*frcp(1.0f + fexp2((2.0f*LOG2E)*x)); }

// ---------------- f32->bf16 prep (GRU weights + emb_mon tables) ----------------
__global__ __launch_bounds__(256) void k_prep(const float* __restrict__ s0, const float* __restrict__ s1,
                                              const float* __restrict__ s2, const float* __restrict__ s3,
                                              const float* __restrict__ s4,
                                              u16* __restrict__ d0, u16* __restrict__ d1,
                                              u16* __restrict__ d2, u16* __restrict__ d3,
                                              u16* __restrict__ d4){
  int y = blockIdx.y;
  const float* src = y==0?s0 : y==1?s1 : y==2?s2 : y==3?s3 : s4;
  u16* dst         = y==0?d0 : y==1?d1 : y==2?d2 : y==3?d3 : d4;
  int n4 = (y<2 ? 245760 : y<4 ? 344064 : 512000) >> 2;
  int i = blockIdx.x*256 + threadIdx.x;
  if (i < n4){
    float4 v = *(const float4*)(src + (size_t)i*4);
    ushort4 o = { f2bf(v.x), f2bf(v.y), f2bf(v.z), f2bf(v.w) };
    *(ushort4*)(dst + (size_t)i*4) = o;
  }
}

// ---------------- front: visit embedding bags + weight/age linears ----------------
// grid (768,5) block 128. y<3: vis_org[y][row][d]; y>=3: hin2T slots 5,6.
__global__ __launch_bounds__(128) void k_front(const int* __restrict__ vids,
                                               const float* __restrict__ embv,
                                               const float* __restrict__ wv, const float* __restrict__ av,
                                               const float* __restrict__ ww, const float* __restrict__ wb,
                                               const float* __restrict__ aw, const float* __restrict__ ab,
                                               u16* __restrict__ vis_org, u16* __restrict__ hin2T){
  __shared__ int ids[48];
  int y = blockIdx.y, row = blockIdx.x, d = threadIdx.x;
  if (y < 3){
    if (d < 48) ids[d] = vids[((size_t)y*768 + row)*48 + d];
    __syncthreads();
    const float* eb = embv + (size_t)y*2000*128;
    float acc = 0.f;
    #pragma unroll 4
    for (int c = 0; c < 48; ++c){ int id = ids[c]; if (id) acc += eb[(size_t)id*128 + d]; }
    vis_org[((size_t)y*768 + row)*128 + d] = f2bf(acc);
  } else {
    int sidx = y - 3;
    const float* vals = sidx ? av : wv;
    const float* wgt  = sidx ? aw : ww;
    const float* bias = sidx ? ab : wb;
    float v = vals[row];
    float h = (v != 0.f) ? (v * wgt[d] + bias[d]) : 0.f;
    int b = row >> 4, vv = row & 15;
    hin2T[((size_t)(5+sidx)*768 + (size_t)vv*48 + b)*128 + d] = f2bf(h);
  }
}

// ---------------- monitor embedding bag ----------------
// grid (3072,2), block 256: 8 rows/block, 32 lanes/row, 4 d/lane.
__global__ __launch_bounds__(256) void k_embed_mon(const int* __restrict__ mids,
                                                   const u16* __restrict__ embm_b,
                                                   u16* __restrict__ mon_xT){
  int p = blockIdx.y;
  int rid = threadIdx.x >> 5, lane32 = threadIdx.x & 31, d0 = lane32*4;
  __shared__ int ids[8][16];
  if (threadIdx.x < 128){
    int rr = threadIdx.x >> 4, c = threadIdx.x & 15;
    int f = 2*p + (c>>3), cm = c & 7;
    ids[rr][c] = mids[((size_t)f*24576 + (size_t)blockIdx.x*8 + rr)*8 + cm];
  }
  __syncthreads();
  const u16* e1 = embm_b + (size_t)(2*p)*1000*128;
  const u16* e2 = embm_b + (size_t)(2*p+1)*1000*128;
  float a0=0.f,a1=0.f,a2=0.f,a3=0.f;
  #pragma unroll
  for (int c = 0; c < 8; ++c){
    int i1 = ids[rid][c], i2 = ids[rid][8+c];
    if (i1 && i2){
      uint2 a = *(const uint2*)(e1 + (size_t)i1*128 + d0);
      uint2 b = *(const uint2*)(e2 + (size_t)i2*128 + d0);
      a0 += bflo(a.x)*bflo(b.x); a1 += bfhi(a.x)*bfhi(b.x);
      a2 += bflo(a.y)*bflo(b.y); a3 += bfhi(a.y)*bfhi(b.y);
    }
  }
  size_t nm = (size_t)blockIdx.x*8 + rid;
  int bv = (int)(nm >> 5), m = (int)(nm & 31);
  ushort4 o = { f2bf(a0), f2bf(a1), f2bf(a2), f2bf(a3) };
  *(ushort4*)(mon_xT + (size_t)p*24576*128 + ((size_t)m*768 + bv)*128 + d0) = o;
}

// ---------------- fused GRU (pipelined, fast gates) ----------------
// mode 0: grid (48,5) T=32. s<2: A=mon_xT[s], rstride=768*128. s>=2:
//         A=vis_org[s-2], rstride=0 (gi constant). weights mgru[s];
//         out hin2T[slot], slot=0x32140 nibble, [v=(lq*4+r)*48 + b=g].
// mode 1: grid (3,7) T=16. A=hin2T[s], rstride=48*128; weights vgru[vi],
//         vi=0x6514320 nibble; out h2[s][b=g*16+lq*4+r][128].

// raw barrier: drain LDS only; global prefetch stays in flight (T4 idiom).
#define BARRIER() asm volatile("s_waitcnt lgkmcnt(0)\n\ts_barrier" ::: "memory")

#define ALOAD(D, tt) { int t_=(tt); if (t_>=T) t_=0; \
  const u16* p_ = ap + (size_t)t_*rstride; \
  D[0]=*(const bf8*)(p_); D[1]=*(const bf8*)(p_+32); \
  D[2]=*(const bf8*)(p_+64); D[3]=*(const bf8*)(p_+96); }

#define GIMM(G0,G1,G2,D) { \
  f4 t0_={biv[0],biv[0],biv[0],biv[0]}; G0=t0_; \
  f4 t1_={biv[1],biv[1],biv[1],biv[1]}; G1=t1_; \
  f4 t2_={biv[2],biv[2],biv[2],biv[2]}; G2=t2_; \
  G0=mfma16(D[0],wfi[0][0],G0); G0=mfma16(D[1],wfi[0][1],G0); \
  G0=mfma16(D[2],wfi[0][2],G0); G0=mfma16(D[3],wfi[0][3],G0); \
  G1=mfma16(D[0],wfi[1][0],G1); G1=mfma16(D[1],wfi[1][1],G1); \
  G1=mfma16(D[2],wfi[1][2],G1); G1=mfma16(D[3],wfi[1][3],G1); \
  G2=mfma16(D[0],wfi[2][0],G2); G2=mfma16(D[1],wfi[2][1],G2); \
  G2=mfma16(D[2],wfi[2][2],G2); G2=mfma16(D[3],wfi[2][3],G2); }

// declares a0_,a1_,a2_ (gh accumulators) + reads hf from hlds[cur]
#define GHRD() \
  bf8 hf0_=*(const bf8*)&hlds[cur][lr][lq*8]; \
  bf8 hf1_=*(const bf8*)&hlds[cur][lr][32+lq*8]; \
  bf8 hf2_=*(const bf8*)&hlds[cur][lr][64+lq*8]; \
  bf8 hf3_=*(const bf8*)&hlds[cur][lr][96+lq*8]; \
  f4 a0_={bhv[0],bhv[0],bhv[0],bhv[0]}; \
  f4 a1_={bhv[1],bhv[1],bhv[1],bhv[1]}; \
  f4 a2_={bhv[2],bhv[2],bhv[2],bhv[2]}; \
  a0_=mfma16(hf0_,wfh[0][0],a0_); a0_=mfma16(hf1_,wfh[0][1],a0_); \
  a0_=mfma16(hf2_,wfh[0][2],a0_); a0_=mfma16(hf3_,wfh[0][3],a0_); \
  a1_=mfma16(hf0_,wfh[1][0],a1_); a1_=mfma16(hf1_,wfh[1][1],a1_); \
  a1_=mfma16(hf2_,wfh[1][2],a1_); a1_=mfma16(hf3_,wfh[1][3],a1_); \
  a2_=mfma16(hf0_,wfh[2][0],a2_); a2_=mfma16(hf1_,wfh[2][1],a2_); \
  a2_=mfma16(hf2_,wfh[2][2],a2_); a2_=mfma16(hf3_,wfh[2][3],a2_);

// consumes G*, a*_ -> h_{t+1}; write LDS; raw barrier; flip cur
#define GATES(G0,G1,G2) { int nxt_=cur^1; \
  _Pragma("unroll") \
  for (int r=0;r<4;++r){ \
    float rr_=sigm(G0[r]+a0_[r]); \
    float zz_=sigm(G1[r]+a1_[r]); \
    float nn_=tanh_f(G2[r]+rr_*a2_[r]); \
    float hv_=(1.0f-zz_)*nn_+zz_*hp[r]; hp[r]=hv_; \
    hlds[nxt_][lq*4+r][w*16+lr]=f2bf(hv_); } \
  BARRIER(); cur=nxt_; }

#define STEP0(G0,G1,G2) { \
  f4 a0_={bhv[0],bhv[0],bhv[0],bhv[0]}; \
  f4 a1_={bhv[1],bhv[1],bhv[1],bhv[1]}; \
  f4 a2_={bhv[2],bhv[2],bhv[2],bhv[2]}; \
  GATES(G0,G1,G2); }

// full pipelined step: consume gi(t) from G*, rebuild G* = gi(t+2) from SN,
// then refill SN with A(t+4) (stays in flight 2 iterations).
#define STEPB(G0,G1,G2,SN,tt) { \
  GHRD(); \
  GATES(G0,G1,G2); \
  if ((tt)+2 < T){ GIMM(G0,G1,G2,SN); } \
  ALOAD(SN,(tt)+4); }

__global__ __launch_bounds__(512, 2) void k_gru(int mode,
    const u16* __restrict__ Asrc, const u16* __restrict__ Asrc2,
    const u16* __restrict__ Wih, const float* __restrict__ bih,
    const u16* __restrict__ Whh, const float* __restrict__ bhh,
    u16* __restrict__ hout, int T){
  int s = blockIdx.y, g = blockIdx.x;
  const u16* A; size_t rstride; u16* ho; int widx;
  if (mode == 0){
    if (s < 2){ A = Asrc + (size_t)s*24576*128; rstride = 768*128; }
    else      { A = Asrc2 + (size_t)(s-2)*768*128; rstride = 0; }
    widx = s;
    int slot = (0x32140u >> (4*s)) & 15;
    ho = hout + (size_t)slot*768*128;
  } else {
    A = Asrc + (size_t)s*768*128; rstride = 48*128;
    widx = (0x6514320u >> (4*s)) & 15;
    ho = hout + (size_t)s*48*128;
  }
  const u16* Wi = Wih + (size_t)widx*384*128;
  const u16* Wh = Whh + (size_t)widx*384*128;
  const float* bi = bih + (size_t)widx*384;
  const float* bh = bhh + (size_t)widx*384;

  int w = threadIdx.x >> 6, l = threadIdx.x & 63;
  int lr = l & 15, lq = l >> 4;

  // wave w owns gate-col-chunk w*16..+16 of r,z,n (tiles w, 8+w, 16+w)
  bf8 wfi[3][4], wfh[3][4]; float biv[3], bhv[3];
  #pragma unroll
  for (int j = 0; j < 3; ++j){
    int colb = (w + 8*j)*16;
    const u16* wpi = Wi + (size_t)(colb + lr)*128 + lq*8;
    const u16* wph = Wh + (size_t)(colb + lr)*128 + lq*8;
    #pragma unroll
    for (int kt = 0; kt < 4; ++kt){
      wfi[j][kt] = *(const bf8*)(wpi + kt*32);
      wfh[j][kt] = *(const bf8*)(wph + kt*32);
    }
    biv[j] = bi[colb + lr];
    bhv[j] = bh[colb + lr];
  }

  const u16* ap = A + (size_t)(g*16 + lr)*128 + lq*8;
  __shared__ u16 hlds[2][16][132];   // 66-dword row stride: conflict-free b128
  float hp[4] = {0.f,0.f,0.f,0.f};
  int cur = 0;

  if (rstride){
    bf8 S0[4], S1[4];
    f4 gE0,gE1,gE2, gO0,gO1,gO2;
    ALOAD(S0,0); ALOAD(S1,1);
    GIMM(gE0,gE1,gE2,S0); ALOAD(S0,2);      // gi(0); A(2) in flight
    GIMM(gO0,gO1,gO2,S1); ALOAD(S1,3);      // gi(1); A(3) in flight
    STEP0(gE0,gE1,gE2);                     // step 0 (gh = bhh)
    GIMM(gE0,gE1,gE2,S0); ALOAD(S0,4);      // gi(2); A(4) in flight
    STEPB(gO0,gO1,gO2,S1,1);                // consume gi(1), build gi(3)
    for (int t = 2; t < T; t += 2){
      STEPB(gE0,gE1,gE2,S0,t);
      STEPB(gO0,gO1,gO2,S1,t+1);
    }
  } else {
    bf8 S0[4];
    f4 gE0,gE1,gE2;
    ALOAD(S0,0);
    GIMM(gE0,gE1,gE2,S0);                   // constant gi, computed once
    STEP0(gE0,gE1,gE2);
    for (int t = 1; t < T; ++t){
      GHRD();
      GATES(gE0,gE1,gE2);
    }
  }

  if (mode == 0){
    #pragma unroll
    for (int r = 0; r < 4; ++r)
      ho[((size_t)(lq*4+r)*48 + g)*128 + w*16 + lr] = f2bf(hp[r]);
  } else {
    #pragma unroll
    for (int r = 0; r < 4; ++r)
      ho[((size_t)(g*16 + lq*4 + r))*128 + w*16 + lr] = f2bf(hp[r]);
  }
}

// ---------------- final projection ----------------
__global__ __launch_bounds__(256) void k_final(const u16* __restrict__ h2,
                                               const float* __restrict__ W,
                                               const float* __restrict__ Bias,
                                               float* __restrict__ out){
  int b = blockIdx.x, t = threadIdx.x;
  __shared__ float emb[896];
  for (int i = t; i < 896; i += 256){
    int j = i >> 7, d = i & 127;
    float v = bf2f(h2[((size_t)j*48 + b)*128 + d]);
    if (j >= 1 && j <= 3) v *= 2.0f;   // slots 1..3 appear twice in reference sum
    emb[i] = fmaxf(v, 0.f);
  }
  __syncthreads();
  float acc = Bias[t];
  const float* wp = W + (size_t)t*896;
  for (int i = 0; i < 896; i += 8){
    float4 w0 = *(const float4*)(wp + i);
    float4 w1 = *(const float4*)(wp + i + 4);
    acc += w0.x*emb[i]   + w0.y*emb[i+1] + w0.z*emb[i+2] + w0.w*emb[i+3];
    acc += w1.x*emb[i+4] + w1.y*emb[i+5] + w1.z*emb[i+6] + w1.w*emb[i+7];
  }
  out[(size_t)b*256 + t] = acc;
}

extern "C" void kernel_launch(void* const* d_in, const int* in_sizes, int n_in,
                              void* d_out, int out_size, void* d_ws, size_t ws_size,
                              hipStream_t stream){
  const int*   visit_ids   = (const int*)d_in[0];
  const int*   mon_ids     = (const int*)d_in[1];
  const float* weight_vals = (const float*)d_in[2];
  const float* age_vals    = (const float*)d_in[3];
  const float* emb_visit   = (const float*)d_in[4];
  const float* emb_mon     = (const float*)d_in[5];
  const float* mgru_Wih    = (const float*)d_in[6];
  const float* mgru_Whh    = (const float*)d_in[7];
  const float* mgru_bih    = (const float*)d_in[8];
  const float* mgru_bhh    = (const float*)d_in[9];
  const float* vgru_Wih    = (const float*)d_in[10];
  const float* vgru_Whh    = (const float*)d_in[11];
  const float* vgru_bih    = (const float*)d_in[12];
  const float* vgru_bhh    = (const float*)d_in[13];
  const float* fc_w_w      = (const float*)d_in[14];
  const float* fc_w_b      = (const float*)d_in[15];
  const float* fc_a_w      = (const float*)d_in[16];
  const float* fc_a_b      = (const float*)d_in[17];
  const float* fc_out_w    = (const float*)d_in[18];
  const float* fc_out_b    = (const float*)d_in[19];

  char* ws = (char*)d_ws;
  size_t o = 0;
  u16* mWih_b  = (u16*)(ws+o); o += 5ull*384*128*2;
  u16* mWhh_b  = (u16*)(ws+o); o += 5ull*384*128*2;
  u16* vWih_b  = (u16*)(ws+o); o += 7ull*384*128*2;
  u16* vWhh_b  = (u16*)(ws+o); o += 7ull*384*128*2;
  u16* embm_b  = (u16*)(ws+o); o += 4ull*1000*128*2;
  u16* mon_xT  = (u16*)(ws+o); o += 2ull*24576*128*2;    // [p][m*768+bv][128]
  u16* vis_org = (u16*)(ws+o); o += 3ull*768*128*2;
  u16* hin2T   = (u16*)(ws+o); o += 7ull*768*128*2;      // [slot][v*48+b][128]
  u16* h2      = (u16*)(ws+o); o += 7ull*48*128*2;       // ~17.6 MB total

  k_prep<<<dim3(500,5), 256, 0, stream>>>(mgru_Wih, mgru_Whh, vgru_Wih, vgru_Whh, emb_mon,
                                          mWih_b, mWhh_b, vWih_b, vWhh_b, embm_b);
  k_front<<<dim3(768,5), 128, 0, stream>>>(visit_ids, emb_visit,
                                           weight_vals, age_vals, fc_w_w, fc_w_b, fc_a_w, fc_a_b,
                                           vis_org, hin2T);
  k_embed_mon<<<dim3(3072,2), 256, 0, stream>>>(mon_ids, embm_b, mon_xT);
  // monitor-level fused GRU: 5 streams -> hin2T slots {0,4,1,2,3}
  k_gru<<<dim3(48,5), 512, 0, stream>>>(0, mon_xT, vis_org,
                                        mWih_b, mgru_bih, mWhh_b, mgru_bhh, hin2T, 32);
  // visit-level fused GRU: 7 streams -> h2
  k_gru<<<dim3(3,7), 512, 0, stream>>>(1, hin2T, (const u16*)0,
                                       vWih_b, vgru_bih, vWhh_b, vgru_bhh, h2, 16);
  k_final<<<48, 256, 0, stream>>>(h2, fc_out_w, fc_out_b, (float*)d_out);
}